// Round 3
// 353.614 us; speedup vs baseline: 1.1246x; 1.1246x over previous
//
#include <hip/hip_runtime.h>

// ErosionLayer: B=16, W=512, ITERS=10, fp32. PASSING numeric recipe (r5..r13,
// absmax 0.02734375): XLA-style greedy FMA via explicit fmaf() at exact sites,
// contract(off) elsewhere, correctly-rounded fp32 div/sqrt. DO NOT change op
// order or fusion sites (cell_math is the frozen recipe).
//
// r14: 2-step fusion with halo recompute (HH=8). Passed twice, but contains a
// LATENT INTRA-DISPATCH RACE: phase 1 reads halo-row s/w/v (step k-1, owned by
// neighbor blocks) from the same arrays neighbor phase 2 writes (step k+1)
// in the same dispatch. Survived only because 2-blocks/CU, 1024-block lockstep
// kept neighbors phase-aligned (violates CDNA G16: no dispatch-timing deps).
// r15/r16 FAILED (absmax 2.19/2.44): changed schedule geometry (HH=4, 2048
// blocks, 3-4 blocks/CU, ragged rounds) -> neighbor skew crossed the
// read->write window -> halo s/w/v reads saw 2-steps-ahead values. The r15
// "gather radius" theory was wrong (widening halo in r16 changed nothing; the
// eps-weight is <=2.4e-7 against bounded values -> could never give absmax 2).
//
// r17 (this round): RACE ELIMINATED — ping-pong double-buffered s/w/v across
// dispatches (read set-in written only by previous dispatch; write set-out).
// Zero extra traffic/registers; ws grows to 8 arrays (128 MiB) with graceful
// single-buffer fallback if ws_size is short. Occupancy push retained: HH=4,
// A = 12 rows [r0-4, r0+7], B = 8 rows [r0-2, r0+5] (covers the [-2,+2]
// worst-case gather radius incl. fp rounding), LDS 40 KiB/block,
// __launch_bounds__(512,6) -> 3 blocks/CU, 24 waves/CU (r14 measured
// Occupancy 20%, VALUBusy 58% at 72 VGPR / 2 blocks/CU). float4 staging.
// cell_math untouched; fusion is bit-equivalent to sequential stepping.
// FINAL skips dead s/w/v stores.
#pragma clang fp contract(off)

constexpr int WW   = 512;
constexpr int NPIX = WW * WW;      // 2^18
constexpr int NTOT = 16 * NPIX;    // 4194304
constexpr int HH   = 4;            // owned rows per block
constexpr int AR   = 12;           // LDS rows [r0-4, r0+7]
constexpr int BR   = 8;            // LDS rows [r0-2, r0+5]
constexpr int NBLK = 16 * (WW / HH);   // 2048

// FROZEN r5/r6 math; all terrain reads from an LDS tile with row offset.
__device__ __forceinline__ void cell_math(
    const float* __restrict__ lds, int rowOfs, int r, int c,
    float rain_v, float gno_v,
    float rr, float evapr, float minhd, float heps, float gravr, float sccr,
    float diss, float depo,
    float& s_io, float& w_io, float& v_io, float& t_out, bool fin)
{
    #pragma clang fp contract(off)
    const float CELLW = 0.390625f;            // 200/512, exact

    float t_c = lds[(r - rowOfs) * WW + c];

    float w = fmaf(rr, rain_v, w_io);

    float dx, dy;
    if      (r == 0)      dx = 0.5f * fmaf(t_c, 1.1f, -t_c);
    else if (r == WW - 1) dx = 0.5f * fmaf(t_c, 0.9f, -t_c);
    else dx = 0.5f * (lds[(r + 1 - rowOfs) * WW + c] - lds[(r - 1 - rowOfs) * WW + c]);
    if      (c == 0)      dy = 0.5f * fmaf(t_c, 1.1f, -t_c);
    else if (c == WW - 1) dy = 0.5f * fmaf(t_c, 0.9f, -t_c);
    else dy = 0.5f * (lds[(r - rowOfs) * WW + c + 1] - lds[(r - rowOfs) * WW + c - 1]);

    float mag = sqrtf(fmaf(dx, dx, dy * dy) + 1e-11f);
    float rX  = gno_v;
    float rY  = sqrtf(fmaf(-rX, rX, 1.0f));   // 1 - rX*rX -> fnma
    float factor = fmaxf(1e-10f - mag, 0.0f); // always 0; kept for fidelity
    float den = mag + factor;
    float fdx = fmaf(factor, rX, dx) / den;   // |fdx| <= 1 + ~3ulp
    float fdy = fmaf(factor, rY, dy) / den;   // |fdy| <= 1 + ~3ulp

    float fx  = (float)c + (-fdx);
    float fy  = (float)r + (-fdy);
    float x0f = floorf(fx), y0f = floorf(fy);
    float wx1 = fx - x0f;
    float wy1 = fy - y0f;
    int x0 = (int)x0f, y0 = (int)y0f;
    int x1 = x0 + 1,   y1 = y0 + 1;

    bool vx0 = (x0 >= 0) & (x0 < WW);
    bool vx1 = (x1 >= 0) & (x1 < WW);
    bool vy0 = (y0 >= 0) & (y0 < WW);
    bool vy1 = (y1 >= 0) & (y1 < WW);
    int x0c = min(max(x0, 0), WW - 1), x1c = min(max(x1, 0), WW - 1);
    int y0c = min(max(y0, 0), WW - 1), y1c = min(max(y1, 0), WW - 1);
    int ty0 = y0c - rowOfs, ty1 = y1c - rowOfs;   // in-tile by [-2,+2] proof

    float g00 = (vx0 && vy0) ? (lds[ty0 * WW + x0c] - 1.0f) : 0.0f;
    float g10 = (vx1 && vy0) ? (lds[ty0 * WW + x1c] - 1.0f) : 0.0f;
    float g01 = (vx0 && vy1) ? (lds[ty1 * WW + x0c] - 1.0f) : 0.0f;
    float g11 = (vx1 && vy1) ? (lds[ty1 * WW + x1c] - 1.0f) : 0.0f;

    float wx0 = 1.0f - wx1;
    float wy0 = 1.0f - wy1;
    float rowA = fmaf(wx0, g00, wx1 * g10);
    float rowB = fmaf(wx0, g01, wx1 * g11);
    float bil  = fmaf(wy0, rowA, wy1 * rowB);
    float neighbor = bil + 1.0f;

    float hd = t_c - neighbor;

    float v = v_io;
    float s = s_io;

    float hds  = ((hd - heps) > 0.0f) ? 1.0f : 0.0f;  // sign(relu(hd-eps))
    float nhd  = hds * fmaxf(hd, minhd);
    float q1 = nhd / CELLW;
    float q2 = q1 * v;
    float q3 = q2 * w;
    float sdiff = fmaf(-q3, sccr, s);                 // s - sed_cap
    float ftb   = (hd < 0.0f) ? 1.0f : 0.0f;          // relu(sign(-hd))
    float first = fminf(fmaxf(-hd, 0.0f), s);
    float ra = fmaxf(sdiff * depo, 0.0f);
    float rb = fmaxf((-sdiff) * diss, 0.0f);
    float deparg = fmaf(1.0f - ftb, ra - rb, first);
    float dep    = fmaxf(-fmaxf(hd, 0.0f), deparg);

    float s_new = s - dep;
    float t_new = t_c + dep;

    float rn = fmaxf(-fdy, 0.0f);
    float rm = fmaxf(1.0f - fabsf(fdy), 0.0f);
    float rp = fmaxf(fdy, 0.0f);

    float s1 = (c == WW - 1) ? 0.0f : rn * s_new;
    float s3 = (c == 0)      ? 0.0f : rp * s_new;
    s_io = fmaf(rm, s_new, s1) + s3;

    float w1 = (c == WW - 1) ? 0.0f : rn * w;
    float w3 = (c == 0)      ? 0.0f : rp * w;
    float wd = fmaf(rm, w, w1) + w3;
    w_io = wd * (1.0f - evapr);

    v_io = (gravr * hd) / CELLW;

    if (fin) {
        float aa = fmaf(-t_new, 2.0f, 1.0f);          // 1 - t*2 -> fnma
        float bq = 1.0f + aa;
        t_out = fmaxf(bq, 0.0f) - 1.0f;
    } else {
        t_out = t_new;
    }
}

template <bool FIRST, bool FINAL>
__global__ __launch_bounds__(512, 6) void erosion_fused(
    const float* __restrict__ tin, float* __restrict__ tout,
    const float* __restrict__ sed_in, const float* __restrict__ wat_in,
    const float* __restrict__ vel_in,
    float* __restrict__ sed_out, float* __restrict__ wat_out,
    float* __restrict__ vel_out,
    const float* __restrict__ rain0, const float* __restrict__ gno0,
    const float* __restrict__ rain1, const float* __restrict__ gno1,
    const float* __restrict__ s_rain_rate, const float* __restrict__ s_evap,
    const float* __restrict__ s_minhd, const float* __restrict__ s_heps,
    const float* __restrict__ s_grav, const float* __restrict__ s_scc,
    const float* __restrict__ s_diss, const float* __restrict__ s_depo)
{
    #pragma clang fp contract(off)
    __shared__ float A[AR * WW];    // terrain k-1, rows [r0-4, r0+7]
    __shared__ float B[BR * WW];    // terrain k,   rows [r0-2, r0+5]

    const int c   = threadIdx.x;
    const int img = blockIdx.x >> 7;           // 128 tiles per image
    const int r0  = (blockIdx.x & 127) * HH;
    const float* tb = tin + (size_t)img * NPIX;

    float rr    = fmaxf(s_rain_rate[0], 0.0f);
    float evapr = fmaxf(s_evap[0], 0.0f);
    float minhd = s_minhd[0];
    float heps  = s_heps[0];
    float gravr = fmaxf(s_grav[0], 0.0f);
    float sccr  = fmaxf(s_scc[0], 0.0f);
    float diss  = s_diss[0];
    float depo  = s_depo[0];

    // ---- stage terrain k-1 rows [r0-4, r0+7] (float4; transform if FIRST)
    // 4 groups of 128 threads; group rg loads rows {rg, rg+4, rg+8}; 128
    // float4 = full 512-col row each. Exact cover of tile rows 0..11.
    {
        const int rg = c >> 7;               // 0..3
        const int c4 = (c & 127) << 2;       // column start (float4 aligned)
        #pragma unroll
        for (int j = 0; j < 3; ++j) {
            int ridx = j * 4 + rg;           // 0..11, each exactly once
            int y = r0 - 4 + ridx;
            if (y >= 0 && y < WW) {
                float4 v = *reinterpret_cast<const float4*>(tb + y * WW + c4);
                if (FIRST) {
                    v.x = (1.0f - v.x) / 2.0f;
                    v.y = (1.0f - v.y) / 2.0f;
                    v.z = (1.0f - v.z) / 2.0f;
                    v.w = (1.0f - v.w) / 2.0f;
                }
                *reinterpret_cast<float4*>(&A[ridx * WW + c4]) = v;
            }
        }
    }
    __syncthreads();

    // ---- phase 1: step k over extended rows [r0-2, r0+5] ----
    // s/w/v read from set-IN (written only by the PREVIOUS dispatch: no
    // intra-dispatch aliasing with any block's phase-2 stores).
    float sK[HH], wK[HH], vK[HH];
    #pragma unroll
    for (int i = 0; i < BR; ++i) {
        int x = r0 - 2 + i;
        if (x >= 0 && x < WW) {
            float s0, w0, v0;
            if (FIRST) { s0 = 0.0f; w0 = 0.0f; v0 = 0.0f; }
            else {
                int g = img * NPIX + x * WW + c;
                s0 = sed_in[g]; w0 = wat_in[g]; v0 = vel_in[g];
            }
            float tn;
            cell_math(A, r0 - 4, x, c, rain0[x * WW + c], gno0[x * WW + c],
                      rr, evapr, minhd, heps, gravr, sccr, diss, depo,
                      s0, w0, v0, tn, false);
            B[i * WW + c] = tn;
            if (i >= 2 && i <= HH + 1) {        // owned rows: j = i-2 (constant)
                sK[i - 2] = s0; wK[i - 2] = w0; vK[i - 2] = v0;
            }
        }
    }
    __syncthreads();

    // ---- phase 2: step k+1 over owned rows [r0, r0+3] ----
    #pragma unroll
    for (int j = 0; j < HH; ++j) {
        int x = r0 + j;
        float s0 = sK[j], w0 = wK[j], v0 = vK[j];
        float tn;
        cell_math(B, r0 - 2, x, c, rain1[x * WW + c], gno1[x * WW + c],
                  rr, evapr, minhd, heps, gravr, sccr, diss, depo,
                  s0, w0, v0, tn, FINAL);
        int g = img * NPIX + x * WW + c;
        tout[g] = tn;
        if (!FINAL) { sed_out[g] = s0; wat_out[g] = w0; vel_out[g] = v0; }
    }
}

extern "C" void kernel_launch(void* const* d_in, const int* in_sizes, int n_in,
                              void* d_out, int out_size, void* d_ws, size_t ws_size,
                              hipStream_t stream) {
    const float* in_terr    = (const float*)d_in[0];
    const float* rain_all   = (const float*)d_in[1];  // (1,10,W,W)
    const float* gnoise_all = (const float*)d_in[2];  // (1,10,W,W)
    const float* p_rr       = (const float*)d_in[3];
    const float* p_evap     = (const float*)d_in[4];
    const float* p_minhd    = (const float*)d_in[5];
    const float* p_heps     = (const float*)d_in[6];
    const float* p_grav     = (const float*)d_in[7];
    const float* p_scc      = (const float*)d_in[8];
    const float* p_diss     = (const float*)d_in[9];
    const float* p_depo     = (const float*)d_in[10];

    float* T0  = (float*)d_out;          // final output
    float* ws  = (float*)d_ws;
    float* T1  = ws;
    float* T2  = ws + (size_t)NTOT;
    float* sA  = ws + (size_t)2 * NTOT;
    float* wA  = ws + (size_t)3 * NTOT;
    float* vA  = ws + (size_t)4 * NTOT;
    float* sB, * wB, * vB;
    if (ws_size >= (size_t)8 * NTOT * sizeof(float)) {
        sB = ws + (size_t)5 * NTOT;
        wB = ws + (size_t)6 * NTOT;
        vB = ws + (size_t)7 * NTOT;
    } else {
        // insufficient workspace: fall back to single-buffer (r14 behavior)
        sB = sA; wB = wA; vB = vA;
    }

    dim3 grid(NBLK), block(512);
    #define RN(k) (rain_all   + (size_t)(k) * NPIX)
    #define GN(k) (gnoise_all + (size_t)(k) * NPIX)
    #define SCAL p_rr, p_evap, p_minhd, p_heps, p_grav, p_scc, p_diss, p_depo

    // steps 0+1: in_terr -> T1; s/w/v: (zeros) -> set A
    erosion_fused<true, false><<<grid, block, 0, stream>>>(
        in_terr, T1, sA, wA, vA, sA, wA, vA, RN(0), GN(0), RN(1), GN(1), SCAL);
    // steps 2+3: T1 -> T2; s/w/v: A -> B
    erosion_fused<false, false><<<grid, block, 0, stream>>>(
        T1, T2, sA, wA, vA, sB, wB, vB, RN(2), GN(2), RN(3), GN(3), SCAL);
    // steps 4+5: T2 -> T1; s/w/v: B -> A
    erosion_fused<false, false><<<grid, block, 0, stream>>>(
        T2, T1, sB, wB, vB, sA, wA, vA, RN(4), GN(4), RN(5), GN(5), SCAL);
    // steps 6+7: T1 -> T2; s/w/v: A -> B
    erosion_fused<false, false><<<grid, block, 0, stream>>>(
        T1, T2, sA, wA, vA, sB, wB, vB, RN(6), GN(6), RN(7), GN(7), SCAL);
    // steps 8+9: T2 -> T0 (= d_out), final transform; s/w/v: B -> (dead)
    erosion_fused<false, true><<<grid, block, 0, stream>>>(
        T2, T0, sB, wB, vB, sA, wA, vA, RN(8), GN(8), RN(9), GN(9), SCAL);

    #undef RN
    #undef GN
    #undef SCAL
}

// Round 4
// 322.624 us; speedup vs baseline: 1.2326x; 1.0961x over previous
//
#include <hip/hip_runtime.h>

// ErosionLayer: B=16, W=512, ITERS=10, fp32. PASSING numeric recipe (r5..r13,
// absmax 0.02734375): XLA-style greedy FMA via explicit fmaf() at exact sites,
// contract(off) elsewhere, correctly-rounded fp32 div/sqrt. cell_math op order
// is the frozen recipe -- only PROVABLY bit-exact simplifications allowed.
//
// r14: 2-step fusion w/ halo recompute (HH=8) -- had latent intra-dispatch
// race on s/w/v halo rows (passed only by schedule luck).
// r15/r16 FAILED: race exposed by schedule-geometry change (not halo radius).
// r17 PASSED 353.6us: race eliminated via ping-pong dbuf of s/w/v across
// dispatches; HH=4; measured VALUBusy 94-98%, Occ 66%, HBM 19-30% -> now
// VALU-ISSUE-BOUND. absmax 0.02734375 exact.
//
// r18 (this round): reduce VALU work, keep dbuf race fix.
//  (a) Bit-exact dead-code removal: mag = sqrtf(>=1e-11) >= 3.16e-6 > 1e-10
//      ==> factor = relu(1e-10-mag) == 0 always ==> rY (full sqrt seq), both
//      fmaf(factor,..) and den=mag+0 removed. fmaf(0,rX,dx)=dx exactly; the
//      only hazard (-0 -> +0 sign flip) is absorbed: fx=c-(+-0)=c, rn/rm/rp
//      yield identical zeros. ~12 of ~86 VALU instrs/cell saved, 0 ulp change.
//  (b) HH=8: halo recompute ratio (2HH+4)/(2HH) = 1.25 vs HH=4's 1.5
//      (-17% evals). A = 16 rows [r0-4, r0+11], B = 12 rows [r0-2, r0+9]
//      (correct [-2,+2] worst-case gather radius incl. fp rounding), LDS
//      56 KiB -> 2 blocks/CU, 16 waves/CU. Measured busy-vs-occupancy curve
//      (6.5 waves->58%, 21 waves->96%) predicts ~85-92% busy at 16 waves;
//      work reduction dominates. __launch_bounds__(512,4) (VGPR cap 128,
//      natural ~48-64, no spill). Grid 1024 = exactly 2 residency rounds.
// Fusion remains bit-equivalent to sequential stepping. FINAL skips dead
// s/w/v stores.
#pragma clang fp contract(off)

constexpr int WW   = 512;
constexpr int NPIX = WW * WW;      // 2^18
constexpr int NTOT = 16 * NPIX;    // 4194304
constexpr int HH   = 8;            // owned rows per block
constexpr int AR   = 16;           // LDS rows [r0-4, r0+11]
constexpr int BR   = 12;           // LDS rows [r0-2, r0+9]
constexpr int NBLK = 16 * (WW / HH);   // 1024

// FROZEN r5/r6 math (+ r18 provably-bit-exact factor/rY/den removal);
// all terrain reads from an LDS tile with row offset.
__device__ __forceinline__ void cell_math(
    const float* __restrict__ lds, int rowOfs, int r, int c,
    float rain_v, float gno_v,
    float rr, float evapr, float minhd, float heps, float gravr, float sccr,
    float diss, float depo,
    float& s_io, float& w_io, float& v_io, float& t_out, bool fin)
{
    #pragma clang fp contract(off)
    const float CELLW = 0.390625f;            // 200/512, exact

    float t_c = lds[(r - rowOfs) * WW + c];

    float w = fmaf(rr, rain_v, w_io);

    float dx, dy;
    if      (r == 0)      dx = 0.5f * fmaf(t_c, 1.1f, -t_c);
    else if (r == WW - 1) dx = 0.5f * fmaf(t_c, 0.9f, -t_c);
    else dx = 0.5f * (lds[(r + 1 - rowOfs) * WW + c] - lds[(r - 1 - rowOfs) * WW + c]);
    if      (c == 0)      dy = 0.5f * fmaf(t_c, 1.1f, -t_c);
    else if (c == WW - 1) dy = 0.5f * fmaf(t_c, 0.9f, -t_c);
    else dy = 0.5f * (lds[(r - rowOfs) * WW + c + 1] - lds[(r - rowOfs) * WW + c - 1]);

    float mag = sqrtf(fmaf(dx, dx, dy * dy) + 1e-11f);
    // r18 bit-exact DCE: mag >= sqrt(1e-11) = 3.16e-6 > 1e-10, so
    // factor = relu(1e-10 - mag) == 0, rY unused, den = mag + 0 = mag.
    // fmaf(0, rX, dx) == dx (sign-of-zero flip absorbed downstream).
    float fdx = dx / mag;                     // |fdx| <= 1 + ~3ulp
    float fdy = dy / mag;                     // |fdy| <= 1 + ~3ulp

    float fx  = (float)c + (-fdx);
    float fy  = (float)r + (-fdy);
    float x0f = floorf(fx), y0f = floorf(fy);
    float wx1 = fx - x0f;
    float wy1 = fy - y0f;
    int x0 = (int)x0f, y0 = (int)y0f;
    int x1 = x0 + 1,   y1 = y0 + 1;

    bool vx0 = (x0 >= 0) & (x0 < WW);
    bool vx1 = (x1 >= 0) & (x1 < WW);
    bool vy0 = (y0 >= 0) & (y0 < WW);
    bool vy1 = (y1 >= 0) & (y1 < WW);
    int x0c = min(max(x0, 0), WW - 1), x1c = min(max(x1, 0), WW - 1);
    int y0c = min(max(y0, 0), WW - 1), y1c = min(max(y1, 0), WW - 1);
    int ty0 = y0c - rowOfs, ty1 = y1c - rowOfs;   // in-tile by [-2,+2] proof

    float g00 = (vx0 && vy0) ? (lds[ty0 * WW + x0c] - 1.0f) : 0.0f;
    float g10 = (vx1 && vy0) ? (lds[ty0 * WW + x1c] - 1.0f) : 0.0f;
    float g01 = (vx0 && vy1) ? (lds[ty1 * WW + x0c] - 1.0f) : 0.0f;
    float g11 = (vx1 && vy1) ? (lds[ty1 * WW + x1c] - 1.0f) : 0.0f;

    float wx0 = 1.0f - wx1;
    float wy0 = 1.0f - wy1;
    float rowA = fmaf(wx0, g00, wx1 * g10);
    float rowB = fmaf(wx0, g01, wx1 * g11);
    float bil  = fmaf(wy0, rowA, wy1 * rowB);
    float neighbor = bil + 1.0f;

    float hd = t_c - neighbor;

    float v = v_io;
    float s = s_io;

    float hds  = ((hd - heps) > 0.0f) ? 1.0f : 0.0f;  // sign(relu(hd-eps))
    float nhd  = hds * fmaxf(hd, minhd);
    float q1 = nhd / CELLW;
    float q2 = q1 * v;
    float q3 = q2 * w;
    float sdiff = fmaf(-q3, sccr, s);                 // s - sed_cap
    float ftb   = (hd < 0.0f) ? 1.0f : 0.0f;          // relu(sign(-hd))
    float first = fminf(fmaxf(-hd, 0.0f), s);
    float ra = fmaxf(sdiff * depo, 0.0f);
    float rb = fmaxf((-sdiff) * diss, 0.0f);
    float deparg = fmaf(1.0f - ftb, ra - rb, first);
    float dep    = fmaxf(-fmaxf(hd, 0.0f), deparg);

    float s_new = s - dep;
    float t_new = t_c + dep;

    float rn = fmaxf(-fdy, 0.0f);
    float rm = fmaxf(1.0f - fabsf(fdy), 0.0f);
    float rp = fmaxf(fdy, 0.0f);

    float s1 = (c == WW - 1) ? 0.0f : rn * s_new;
    float s3 = (c == 0)      ? 0.0f : rp * s_new;
    s_io = fmaf(rm, s_new, s1) + s3;

    float w1 = (c == WW - 1) ? 0.0f : rn * w;
    float w3 = (c == 0)      ? 0.0f : rp * w;
    float wd = fmaf(rm, w, w1) + w3;
    w_io = wd * (1.0f - evapr);

    v_io = (gravr * hd) / CELLW;

    if (fin) {
        float aa = fmaf(-t_new, 2.0f, 1.0f);          // 1 - t*2 -> fnma
        float bq = 1.0f + aa;
        t_out = fmaxf(bq, 0.0f) - 1.0f;
    } else {
        t_out = t_new;
    }
}

template <bool FIRST, bool FINAL>
__global__ __launch_bounds__(512, 4) void erosion_fused(
    const float* __restrict__ tin, float* __restrict__ tout,
    const float* __restrict__ sed_in, const float* __restrict__ wat_in,
    const float* __restrict__ vel_in,
    float* __restrict__ sed_out, float* __restrict__ wat_out,
    float* __restrict__ vel_out,
    const float* __restrict__ rain0, const float* __restrict__ gno0,
    const float* __restrict__ rain1, const float* __restrict__ gno1,
    const float* __restrict__ s_rain_rate, const float* __restrict__ s_evap,
    const float* __restrict__ s_minhd, const float* __restrict__ s_heps,
    const float* __restrict__ s_grav, const float* __restrict__ s_scc,
    const float* __restrict__ s_diss, const float* __restrict__ s_depo)
{
    #pragma clang fp contract(off)
    __shared__ float A[AR * WW];    // terrain k-1, rows [r0-4, r0+11]
    __shared__ float B[BR * WW];    // terrain k,   rows [r0-2, r0+9]

    const int c   = threadIdx.x;
    const int img = blockIdx.x >> 6;           // 64 tiles per image
    const int r0  = (blockIdx.x & 63) * HH;
    const float* tb = tin + (size_t)img * NPIX;

    float rr    = fmaxf(s_rain_rate[0], 0.0f);
    float evapr = fmaxf(s_evap[0], 0.0f);
    float minhd = s_minhd[0];
    float heps  = s_heps[0];
    float gravr = fmaxf(s_grav[0], 0.0f);
    float sccr  = fmaxf(s_scc[0], 0.0f);
    float diss  = s_diss[0];
    float depo  = s_depo[0];

    // ---- stage terrain k-1 rows [r0-4, r0+11] (float4; transform if FIRST)
    // 4 groups of 128 threads; group rg loads rows {rg, rg+4, rg+8, rg+12};
    // 128 float4 = full 512-col row each. Exact cover of tile rows 0..15.
    {
        const int rg = c >> 7;               // 0..3
        const int c4 = (c & 127) << 2;       // column start (float4 aligned)
        #pragma unroll
        for (int j = 0; j < 4; ++j) {
            int ridx = j * 4 + rg;           // 0..15, each exactly once
            int y = r0 - 4 + ridx;
            if (y >= 0 && y < WW) {
                float4 v = *reinterpret_cast<const float4*>(tb + y * WW + c4);
                if (FIRST) {
                    v.x = (1.0f - v.x) / 2.0f;
                    v.y = (1.0f - v.y) / 2.0f;
                    v.z = (1.0f - v.z) / 2.0f;
                    v.w = (1.0f - v.w) / 2.0f;
                }
                *reinterpret_cast<float4*>(&A[ridx * WW + c4]) = v;
            }
        }
    }
    __syncthreads();

    // ---- phase 1: step k over extended rows [r0-2, r0+9] ----
    // s/w/v read from set-IN (written only by the PREVIOUS dispatch: no
    // intra-dispatch aliasing with any block's phase-2 stores).
    float sK[HH], wK[HH], vK[HH];
    #pragma unroll
    for (int i = 0; i < BR; ++i) {
        int x = r0 - 2 + i;
        if (x >= 0 && x < WW) {
            float s0, w0, v0;
            if (FIRST) { s0 = 0.0f; w0 = 0.0f; v0 = 0.0f; }
            else {
                int g = img * NPIX + x * WW + c;
                s0 = sed_in[g]; w0 = wat_in[g]; v0 = vel_in[g];
            }
            float tn;
            cell_math(A, r0 - 4, x, c, rain0[x * WW + c], gno0[x * WW + c],
                      rr, evapr, minhd, heps, gravr, sccr, diss, depo,
                      s0, w0, v0, tn, false);
            B[i * WW + c] = tn;
            if (i >= 2 && i <= HH + 1) {        // owned rows: j = i-2 (constant)
                sK[i - 2] = s0; wK[i - 2] = w0; vK[i - 2] = v0;
            }
        }
    }
    __syncthreads();

    // ---- phase 2: step k+1 over owned rows [r0, r0+7] ----
    #pragma unroll
    for (int j = 0; j < HH; ++j) {
        int x = r0 + j;
        float s0 = sK[j], w0 = wK[j], v0 = vK[j];
        float tn;
        cell_math(B, r0 - 2, x, c, rain1[x * WW + c], gno1[x * WW + c],
                  rr, evapr, minhd, heps, gravr, sccr, diss, depo,
                  s0, w0, v0, tn, FINAL);
        int g = img * NPIX + x * WW + c;
        tout[g] = tn;
        if (!FINAL) { sed_out[g] = s0; wat_out[g] = w0; vel_out[g] = v0; }
    }
}

extern "C" void kernel_launch(void* const* d_in, const int* in_sizes, int n_in,
                              void* d_out, int out_size, void* d_ws, size_t ws_size,
                              hipStream_t stream) {
    const float* in_terr    = (const float*)d_in[0];
    const float* rain_all   = (const float*)d_in[1];  // (1,10,W,W)
    const float* gnoise_all = (const float*)d_in[2];  // (1,10,W,W)
    const float* p_rr       = (const float*)d_in[3];
    const float* p_evap     = (const float*)d_in[4];
    const float* p_minhd    = (const float*)d_in[5];
    const float* p_heps     = (const float*)d_in[6];
    const float* p_grav     = (const float*)d_in[7];
    const float* p_scc      = (const float*)d_in[8];
    const float* p_diss     = (const float*)d_in[9];
    const float* p_depo     = (const float*)d_in[10];

    float* T0  = (float*)d_out;          // final output
    float* ws  = (float*)d_ws;
    float* T1  = ws;
    float* T2  = ws + (size_t)NTOT;
    float* sA  = ws + (size_t)2 * NTOT;
    float* wA  = ws + (size_t)3 * NTOT;
    float* vA  = ws + (size_t)4 * NTOT;
    float* sB, * wB, * vB;
    if (ws_size >= (size_t)8 * NTOT * sizeof(float)) {
        sB = ws + (size_t)5 * NTOT;
        wB = ws + (size_t)6 * NTOT;
        vB = ws + (size_t)7 * NTOT;
    } else {
        // insufficient workspace: fall back to single-buffer (r14 behavior)
        sB = sA; wB = wA; vB = vA;
    }

    dim3 grid(NBLK), block(512);
    #define RN(k) (rain_all   + (size_t)(k) * NPIX)
    #define GN(k) (gnoise_all + (size_t)(k) * NPIX)
    #define SCAL p_rr, p_evap, p_minhd, p_heps, p_grav, p_scc, p_diss, p_depo

    // steps 0+1: in_terr -> T1; s/w/v: (zeros) -> set A
    erosion_fused<true, false><<<grid, block, 0, stream>>>(
        in_terr, T1, sA, wA, vA, sA, wA, vA, RN(0), GN(0), RN(1), GN(1), SCAL);
    // steps 2+3: T1 -> T2; s/w/v: A -> B
    erosion_fused<false, false><<<grid, block, 0, stream>>>(
        T1, T2, sA, wA, vA, sB, wB, vB, RN(2), GN(2), RN(3), GN(3), SCAL);
    // steps 4+5: T2 -> T1; s/w/v: B -> A
    erosion_fused<false, false><<<grid, block, 0, stream>>>(
        T2, T1, sB, wB, vB, sA, wA, vA, RN(4), GN(4), RN(5), GN(5), SCAL);
    // steps 6+7: T1 -> T2; s/w/v: A -> B
    erosion_fused<false, false><<<grid, block, 0, stream>>>(
        T1, T2, sA, wA, vA, sB, wB, vB, RN(6), GN(6), RN(7), GN(7), SCAL);
    // steps 8+9: T2 -> T0 (= d_out), final transform; s/w/v: B -> (dead)
    erosion_fused<false, true><<<grid, block, 0, stream>>>(
        T2, T0, sB, wB, vB, sA, wA, vA, RN(8), GN(8), RN(9), GN(9), SCAL);

    #undef RN
    #undef GN
    #undef SCAL
}